// Round 2
// baseline (194.778 us; speedup 1.0000x reference)
//
#include <hip/hip_runtime.h>
#include <stdint.h>
#include <stddef.h>

typedef __bf16 bf16;
typedef __bf16 bf16x8 __attribute__((ext_vector_type(8)));
typedef __bf16 bf16x4 __attribute__((ext_vector_type(4)));
typedef short short4v __attribute__((ext_vector_type(4)));
typedef float f32x4 __attribute__((ext_vector_type(4)));

#define GAS __attribute__((address_space(1)))
#define LAS __attribute__((address_space(3)))

__device__ __forceinline__ void async_load16(const void* g, void* l) {
  __builtin_amdgcn_global_load_lds((const GAS void*)g, (LAS void*)l, 16, 0, 0);
}

// 16x16x16 bf16 MFMA. C-layout of a 16x16 MFMA == B-layout of this shape,
// so P^T feeds PV straight from registers. Host pass gets a stub.
__device__ __forceinline__ f32x4 mfma16(bf16x4 a, bf16x4 b, f32x4 c) {
#if defined(__HIP_DEVICE_COMPILE__)
#if __has_builtin(__builtin_amdgcn_mfma_f32_16x16x16bf16_1k)
  return __builtin_amdgcn_mfma_f32_16x16x16bf16_1k(
      __builtin_bit_cast(short4v, a), __builtin_bit_cast(short4v, b), c, 0, 0, 0);
#else
  f32x4 d;
  asm volatile("v_mfma_f32_16x16x16_bf16 %0, %1, %2, %3"
               : "=v"(d)
               : "v"(a), "v"(b), "v"(c));
  return d;
#endif
#else
  (void)a; (void)b;
  return c;
#endif
}

// ---------------------------------------------------------------------------
// Kernel 1: fp32 -> bf16 casts, x4 vectorized. Wq pre-scaled by 0.125*log2(e)
// so QK^T lands in the exp2 domain (scores bounded -> no max subtraction).
// ---------------------------------------------------------------------------
__global__ __launch_bounds__(256) void cast_all(
    const float* __restrict__ x, const float* __restrict__ Wq,
    const float* __restrict__ Wk, const float* __restrict__ Wv,
    const float* __restrict__ Wo, bf16* __restrict__ Xh,
    bf16* __restrict__ Wqkv, bf16* __restrict__ Woh) {
  int idx = (blockIdx.x * 256 + threadIdx.x) * 4;
  const float* src;
  bf16* dst;
  float scale = 1.0f;
  if (idx < 4194304) {
    src = x + idx; dst = Xh + idx;
  } else if (idx < 7340032) {
    int j = idx - 4194304;
    if (j < 1048576) {
      src = Wq + j; scale = 0.18033688011112042f;
    } else {
      src = ((j < 2097152) ? Wk : Wv) + (j & 1048575);
    }
    dst = Wqkv + j;
  } else {
    int j = idx - 7340032;
    src = Wo + j; dst = Woh + j;
  }
  float4 v = *(const float4*)src;
  bf16x4 o;
  o[0] = (bf16)(v.x * scale); o[1] = (bf16)(v.y * scale);
  o[2] = (bf16)(v.z * scale); o[3] = (bf16)(v.w * scale);
  *(bf16x4*)dst = o;
}

// ---------------------------------------------------------------------------
// Kernel 2: QKV projection with FUSED RoPE + V-transpose epilogue.
// Q -> Qh [bh][s][64] (linear), K -> Kh [bh][s][64] with the d-dimension
// PRE-SWIZZLED per row (element (s,d) stored at d ^ ((s&7)<<3)) so attn can
// stage K-tiles linearly via global_load_lds and read conflict-free with the
// inverse XOR. V -> Vt[bh][64][2048] with s-within-64 pre-swizzled by d
// (round-15 scheme, unchanged). Both-sides swizzle pattern (m173).
// ---------------------------------------------------------------------------
__global__ __launch_bounds__(256) void gemm_qkv(
    const bf16* __restrict__ A, const bf16* __restrict__ B,
    bf16* __restrict__ Qh, bf16* __restrict__ Kh, bf16* __restrict__ Vt,
    int K) {
  __shared__ __align__(16) bf16 As[128 * 32];
  __shared__ __align__(16) bf16 Bs[128 * 32];
  const int tid = threadIdx.x;
  const int wave = tid >> 6, lane = tid & 63;
  const int bm = blockIdx.y * 128, bn = blockIdx.x * 128;
  const int wm = (wave >> 1) * 64, wn = (wave & 1) * 64;
  const int lrow = lane >> 2, lk = (lane & 3) * 8;
  const int fr = lane & 15, fk = (lane >> 4) * 8;

  f32x4 acc[4][4] = {};

  for (int kt = 0; kt < K; kt += 32) {
    __syncthreads();
#pragma unroll
    for (int c = 0; c < 2; ++c) {
      const int chunk = wave * 2 + c;
      const bf16* ga = A + (size_t)(bm + chunk * 16 + lrow) * K + kt + lk;
      async_load16(ga, (void*)(As + chunk * 512));
      const bf16* gb = B + (size_t)(bn + chunk * 16 + lrow) * K + kt + lk;
      async_load16(gb, (void*)(Bs + chunk * 512));
    }
    __syncthreads();

    bf16x8 af[4], bfr[4];
#pragma unroll
    for (int i = 0; i < 4; ++i)
      af[i] = *(const bf16x8*)&As[(wm + i * 16 + fr) * 32 + fk];
#pragma unroll
    for (int j = 0; j < 4; ++j)
      bfr[j] = *(const bf16x8*)&Bs[(wn + j * 16 + fr) * 32 + fk];
#pragma unroll
    for (int i = 0; i < 4; ++i)
#pragma unroll
      for (int j = 0; j < 4; ++j)
        acc[i][j] =
            __builtin_amdgcn_mfma_f32_16x16x32_bf16(af[i], bfr[j], acc[i][j], 0, 0, 0);
  }

  const int r0 = (lane >> 4) * 4, cc = lane & 15;
  const bool oddl = cc & 1;
#pragma unroll
  for (int i = 0; i < 4; ++i) {
    const int row0 = bm + wm + i * 16 + r0;
    const int b = row0 >> 11, s0 = row0 & 2047;
#pragma unroll
    for (int j = 0; j < 4; ++j) {
      const int col = bn + wn + j * 16 + cc;  // whole wave same region per j
      if (col < 2048) {
        // RoPE: pair partner is lane^1 (col 2k <-> 2k+1)
        const int hcol = col & 1023;
        const int h = hcol >> 6, d = hcol & 63;
        const int ip = d >> 1;
        const float freq = __expf((float)ip * -0.2878231366242557f);
        const bool isK = col >= 1024;
        bf16* dst = (isK ? Kh : Qh) + ((size_t)(b * 16 + h) * 2048) * 64;
#pragma unroll
        for (int r = 0; r < 4; ++r) {
          float own = acc[i][j][r];
          float oth = __shfl_xor(own, 1, 64);
          float sn, cs;
          __sincosf((float)(s0 + r) * freq, &sn, &cs);
          float res = oddl ? (oth * sn + own * cs) : (own * cs - oth * sn);
          // K: d-swizzle by row (bits 3..5 of d; rope pair bit0 unaffected)
          const int dd = isK ? (d ^ (((s0 + r) & 7) << 3)) : d;
          dst[(size_t)(s0 + r) * 64 + dd] = (bf16)res;
        }
      } else {
        const int v = col - 2048, h = v >> 6, d = v & 63;
        bf16x4 o;
#pragma unroll
        for (int r = 0; r < 4; ++r) o[r] = (bf16)acc[i][j][r];
        // pre-swizzled column (XOR touches bits 3..5 only; the 4-run at s0
        // stays contiguous since s0 is 4-aligned)
        const int s2 = (s0 & ~63) | ((s0 ^ ((d & 7) << 3)) & 63);
        *(bf16x4*)&Vt[(((size_t)b * 16 + h) * 64 + d) * 2048 + s2] = o;
      }
    }
  }
}

// ---------------------------------------------------------------------------
// Kernel 2b (out-proj): C(MxN) = A(MxK) @ B(NxK)^T, fp32 out.
// 128x128 tile (256 blocks = exact 1/CU).
// ---------------------------------------------------------------------------
template <typename OutT, int BM, int BN>
__global__ __launch_bounds__(256) void gemm_bt(
    const bf16* __restrict__ A, const bf16* __restrict__ B,
    OutT* __restrict__ C, int M, int N, int K) {
  constexpr int ACH = BM / 16, NCH = (BM + BN) / 16, PW = NCH / 4;
  constexpr int FM = BM / 32, FN = BN / 32;
  __shared__ __align__(16) bf16 As[BM * 32];
  __shared__ __align__(16) bf16 Bs[BN * 32];
  const int tid = threadIdx.x;
  const int wave = tid >> 6, lane = tid & 63;
  const int bm = blockIdx.y * BM, bn = blockIdx.x * BN;
  const int wm = (wave >> 1) * (BM / 2), wn = (wave & 1) * (BN / 2);
  const int lrow = lane >> 2, lk = (lane & 3) * 8;
  const int fr = lane & 15, fk = (lane >> 4) * 8;

  f32x4 acc[FM][FN] = {};

  for (int kt = 0; kt < K; kt += 32) {
    __syncthreads();
#pragma unroll
    for (int c = 0; c < PW; ++c) {
      const int chunk = wave * PW + c;
      if (chunk < ACH) {
        const bf16* ga = A + (size_t)(bm + chunk * 16 + lrow) * K + kt + lk;
        async_load16(ga, (void*)(As + chunk * 512));
      } else {
        const int bc = chunk - ACH;
        const bf16* gb = B + (size_t)(bn + bc * 16 + lrow) * K + kt + lk;
        async_load16(gb, (void*)(Bs + bc * 512));
      }
    }
    __syncthreads();

    bf16x8 af[FM], bfr[FN];
#pragma unroll
    for (int i = 0; i < FM; ++i)
      af[i] = *(const bf16x8*)&As[(wm + i * 16 + fr) * 32 + fk];
#pragma unroll
    for (int j = 0; j < FN; ++j)
      bfr[j] = *(const bf16x8*)&Bs[(wn + j * 16 + fr) * 32 + fk];
#pragma unroll
    for (int i = 0; i < FM; ++i)
#pragma unroll
      for (int j = 0; j < FN; ++j)
        acc[i][j] =
            __builtin_amdgcn_mfma_f32_16x16x32_bf16(af[i], bfr[j], acc[i][j], 0, 0, 0);
  }

  const int r0 = (lane >> 4) * 4, cc = lane & 15;
#pragma unroll
  for (int i = 0; i < FM; ++i)
#pragma unroll
    for (int j = 0; j < FN; ++j)
#pragma unroll
      for (int r = 0; r < 4; ++r)
        C[(size_t)(bm + wm + i * 16 + r0 + r) * N + (bn + wn + j * 16 + cc)] =
            (OutT)acc[i][j][r];
}

// ---------------------------------------------------------------------------
// Kernel 3: causal attention — ROUND 16: flash-block restructure.
// r15 post-mortem: per-iteration chain ~8000 cy (wall = longest block);
// every wave privately pulled K+V (16KB/iter) from L2 and ate the latency
// in-line. Fix (m97/§5-template schedule applied to attn):
//   * Block = 4 waves x 256 threads sharing ONE 128-row Q-tile; K-tile and
//     V-tile staged ONCE per block into LDS via global_load_lds (4x less L2
//     traffic per unit MFMA work).
//   * Double-buffered: stage(i+1) issued BEFORE compute(i); one
//     __syncthreads per iteration (its vmcnt drain = the only stage wait,
//     ~1500cy after issue -> hidden).
//   * K rows are 128B stride -> 16-way bank conflict if linear; Kh is
//     pre-swizzled by the producer (d ^ ((s&7)<<3)), staged linearly, read
//     with the inverse XOR (both-sides pattern, same as V).
//   * pk/av LDS reads hoisted into arrays -> back-to-back issue, one lgkm
//     wait, then pure MFMA burst.
//   * No cross-wave combine: each wave owns 32 q-rows end-to-end; causal
//     tail = wave-uniform skip/mask (<=2 tail tiles per block).
// Grid 512 blocks (16 q-tiles x 32 bh), LPT (longest first), bh&7 = XCD.
// ---------------------------------------------------------------------------
__global__ __launch_bounds__(256, 2) void attn(const bf16* __restrict__ Qh,
                                               const bf16* __restrict__ Kh,
                                               const bf16* __restrict__ Vt,
                                               bf16* __restrict__ Oh) {
  __shared__ __align__(16) bf16 Ks[2][64 * 64];
  __shared__ __align__(16) bf16 Vs[2][64 * 64];
  const int f = blockIdx.x;
  const int j = 15 - (f >> 5);  // LPT: longest (j=15, n=32) dispatch first
  const int bh = f & 31;        // bh&7 == f&7 -> XCD affinity
  const int tid = threadIdx.x, w = tid >> 6, lane = tid & 63;
  const int nlo = lane & 15, g = lane >> 4;
  const int q0 = j * 128, qw0 = q0 + w * 32;  // this wave's 32 q-rows
  const bf16* __restrict__ Qp = Qh + (size_t)bh * 131072;
  const bf16* __restrict__ Kp = Kh + (size_t)bh * 131072;
  const bf16* __restrict__ Vp = Vt + (size_t)bh * 131072;
  const int n = 2 * (j + 1);  // k-tiles for this block

  // Q fragments (B-operand: n=q=nlo, k=d=g*8+..), linear Qh
  bf16x8 aq[2][2];
#pragma unroll
  for (int qb = 0; qb < 2; ++qb)
#pragma unroll
    for (int ks = 0; ks < 2; ++ks)
      aq[qb][ks] =
          *(const bf16x8*)&Qp[(size_t)(qw0 + qb * 16 + nlo) * 64 + ks * 32 + g * 8];

  f32x4 oacc[2][4] = {};  // [qb][d-block], O^T C-layout (m=d, n=q)
  float lsum[2] = {0.f, 0.f};
  const int sw = (nlo & 7) << 3;  // inverse XOR for swizzled LDS reads

  // Staging: 8 chunks of 8 rows per array; wave w owns chunks 2w,2w+1
  // (rows w*16..w*16+15). LDS dst is linear (gload_lds: base + lane*16B).
  const int srow = w * 16 + (lane >> 3);
  const int soff = (lane & 7) * 8;

  auto stage = [&](int buf, int kbase) {
    async_load16(Kp + (size_t)(kbase + srow) * 64 + soff,
                 (void*)(Ks[buf] + w * 1024));
    async_load16(Kp + (size_t)(kbase + srow + 8) * 64 + soff,
                 (void*)(Ks[buf] + w * 1024 + 512));
    async_load16(Vp + (size_t)srow * 2048 + kbase + soff,
                 (void*)(Vs[buf] + w * 1024));
    async_load16(Vp + (size_t)(srow + 8) * 2048 + kbase + soff,
                 (void*)(Vs[buf] + w * 1024 + 512));
  };

  stage(0, 0);
  __syncthreads();  // drains vmcnt -> buf0 staged

  for (int i = 0; i < n; ++i) {
    const int buf = i & 1, kbase = i * 64;
    if (i + 1 < n) stage(buf ^ 1, (i + 1) * 64);  // prefetch next tile

    if (kbase <= qw0 + 31) {  // wave-uniform: any unmasked (q,k) in tile?
      const bf16* __restrict__ Kw = Ks[buf];
      const bf16* __restrict__ Vw = Vs[buf];

      // K fragments: 8x ds_read_b128, swizzle-corrected, back-to-back
      bf16x8 pk[4][2];
#pragma unroll
      for (int ni = 0; ni < 4; ++ni)
#pragma unroll
        for (int ks = 0; ks < 2; ++ks)
          pk[ni][ks] = *(const bf16x8*)&Kw[(ni * 16 + nlo) * 64 +
                                           ((ks * 32 + g * 8) ^ sw)];

      // S^T = K.Q^T, p = exp2(S^T) in regs, l accumulated in-lane
      const bool dg = (kbase + 63 > qw0);  // wave-uniform diagonal flag
      bf16x4 p[2][4];
#pragma unroll
      for (int qb = 0; qb < 2; ++qb) {
        f32x4 st[4] = {};
#pragma unroll
        for (int ks = 0; ks < 2; ++ks)
#pragma unroll
          for (int ni = 0; ni < 4; ++ni)
            st[ni] = __builtin_amdgcn_mfma_f32_16x16x32_bf16(pk[ni][ks], aq[qb][ks],
                                                             st[ni], 0, 0, 0);
        const int qg = qw0 + qb * 16 + nlo;
        if (!dg) {
#pragma unroll
          for (int ni = 0; ni < 4; ++ni)
#pragma unroll
            for (int r = 0; r < 4; ++r) {
              float e = __builtin_amdgcn_exp2f(st[ni][r]);
              lsum[qb] += e;
              p[qb][ni][r] = (bf16)e;
            }
        } else {
#pragma unroll
          for (int ni = 0; ni < 4; ++ni) {
            const int kg0 = kbase + ni * 16 + g * 4;
#pragma unroll
            for (int r = 0; r < 4; ++r) {
              float e = __builtin_amdgcn_exp2f(st[ni][r]);
              e = (kg0 + r <= qg) ? e : 0.0f;
              lsum[qb] += e;
              p[qb][ni][r] = (bf16)e;
            }
          }
        }
      }

      // V fragments: 16x ds_read_b64 hoisted, then pure MFMA burst
      bf16x4 av[4][4];
#pragma unroll
      for (int ni = 0; ni < 4; ++ni)
#pragma unroll
        for (int mi = 0; mi < 4; ++mi)
          av[ni][mi] = *(const bf16x4*)&Vw[(mi * 16 + nlo) * 64 +
                                           ((ni * 16 + g * 4) ^ sw)];
#pragma unroll
      for (int ni = 0; ni < 4; ++ni)
#pragma unroll
        for (int mi = 0; mi < 4; ++mi)
#pragma unroll
          for (int qb = 0; qb < 2; ++qb)
            oacc[qb][mi] = mfma16(av[ni][mi], p[qb][ni], oacc[qb][mi]);
    }

    __syncthreads();  // all waves done with buf; next stage landed
  }

  // finish l: reduce over the 4 g-groups (columns are per-nlo)
#pragma unroll
  for (int qb = 0; qb < 2; ++qb) {
    lsum[qb] += __shfl_xor(lsum[qb], 16, 64);
    lsum[qb] += __shfl_xor(lsum[qb], 32, 64);
  }

  // each wave writes its own rows; no combine needed
  const int bb = bh >> 4, hd = bh & 15;
#pragma unroll
  for (int qb = 0; qb < 2; ++qb) {
    const float inv = 1.0f / lsum[qb];
    const int q = qw0 + qb * 16 + nlo;
#pragma unroll
    for (int mi = 0; mi < 4; ++mi) {
      bf16x4 o;
#pragma unroll
      for (int r = 0; r < 4; ++r) o[r] = (bf16)(oacc[qb][mi][r] * inv);
      *(bf16x4*)&Oh[((size_t)bb * 2048 + q) * 1024 + hd * 64 + mi * 16 + g * 4] = o;
    }
  }
}

// ---------------------------------------------------------------------------
extern "C" void kernel_launch(void* const* d_in, const int* in_sizes, int n_in,
                              void* d_out, int out_size, void* d_ws, size_t ws_size,
                              hipStream_t stream) {
  (void)in_sizes; (void)n_in; (void)out_size; (void)ws_size;
  const float* x = (const float*)d_in[0];
  const float* Wq = (const float*)d_in[1];
  const float* Wk = (const float*)d_in[2];
  const float* Wv = (const float*)d_in[3];
  const float* Wo = (const float*)d_in[4];
  float* out = (float*)d_out;
  char* ws = (char*)d_ws;

  bf16* Xh   = (bf16*)(ws);                 // 4096x1024          8 MB
  bf16* Wqkv = (bf16*)(ws + 8388608);       // 3072x1024          6 MB
  bf16* Woh  = (bf16*)(ws + 14680064);      // 1024x1024          2 MB
  bf16* Qh   = (bf16*)(ws + 16777216);      // [32][2048][64]     8 MB
  bf16* Kh   = (bf16*)(ws + 25165824);      // [32][2048][64]     8 MB (d-swizzled)
  bf16* Vt   = (bf16*)(ws + 33554432);      // [32][64][2048]     8 MB (col-swizzled)
  bf16* Oh   = (bf16*)(ws + 41943040);      // 4096x1024          8 MB

  cast_all<<<8192, 256, 0, stream>>>(x, Wq, Wk, Wv, Wo, Xh, Wqkv, Woh);
  gemm_qkv<<<dim3(24, 32), 256, 0, stream>>>(Xh, Wqkv, Qh, Kh, Vt, 1024);
  attn<<<512, 256, 0, stream>>>(Qh, Kh, Vt, Oh);
  gemm_bt<float, 128, 128><<<dim3(8, 32), 256, 0, stream>>>(Oh, Woh, out, 4096, 1024, 1024);
}

// Round 3
// 189.960 us; speedup vs baseline: 1.0254x; 1.0254x over previous
//
#include <hip/hip_runtime.h>
#include <stdint.h>
#include <stddef.h>

typedef __bf16 bf16;
typedef __bf16 bf16x8 __attribute__((ext_vector_type(8)));
typedef __bf16 bf16x4 __attribute__((ext_vector_type(4)));
typedef short short4v __attribute__((ext_vector_type(4)));
typedef float f32x4 __attribute__((ext_vector_type(4)));

#define GAS __attribute__((address_space(1)))
#define LAS __attribute__((address_space(3)))

__device__ __forceinline__ void async_load16(const void* g, void* l) {
  __builtin_amdgcn_global_load_lds((const GAS void*)g, (LAS void*)l, 16, 0, 0);
}

// 16x16x16 bf16 MFMA. C-layout of a 16x16 MFMA == B-layout of this shape,
// so P^T feeds PV straight from registers. Host pass gets a stub.
__device__ __forceinline__ f32x4 mfma16(bf16x4 a, bf16x4 b, f32x4 c) {
#if defined(__HIP_DEVICE_COMPILE__)
#if __has_builtin(__builtin_amdgcn_mfma_f32_16x16x16bf16_1k)
  return __builtin_amdgcn_mfma_f32_16x16x16bf16_1k(
      __builtin_bit_cast(short4v, a), __builtin_bit_cast(short4v, b), c, 0, 0, 0);
#else
  f32x4 d;
  asm volatile("v_mfma_f32_16x16x16_bf16 %0, %1, %2, %3"
               : "=v"(d)
               : "v"(a), "v"(b), "v"(c));
  return d;
#endif
#else
  (void)a; (void)b;
  return c;
#endif
}

// ---------------------------------------------------------------------------
// Kernel 1: fp32 -> bf16 casts, x4 vectorized. Wq pre-scaled by 0.125*log2(e)
// so QK^T lands in the exp2 domain (scores bounded -> no max subtraction).
// ---------------------------------------------------------------------------
__global__ __launch_bounds__(256) void cast_all(
    const float* __restrict__ x, const float* __restrict__ Wq,
    const float* __restrict__ Wk, const float* __restrict__ Wv,
    const float* __restrict__ Wo, bf16* __restrict__ Xh,
    bf16* __restrict__ Wqkv, bf16* __restrict__ Woh) {
  int idx = (blockIdx.x * 256 + threadIdx.x) * 4;
  const float* src;
  bf16* dst;
  float scale = 1.0f;
  if (idx < 4194304) {
    src = x + idx; dst = Xh + idx;
  } else if (idx < 7340032) {
    int j = idx - 4194304;
    if (j < 1048576) {
      src = Wq + j; scale = 0.18033688011112042f;
    } else {
      src = ((j < 2097152) ? Wk : Wv) + (j & 1048575);
    }
    dst = Wqkv + j;
  } else {
    int j = idx - 7340032;
    src = Wo + j; dst = Woh + j;
  }
  float4 v = *(const float4*)src;
  bf16x4 o;
  o[0] = (bf16)(v.x * scale); o[1] = (bf16)(v.y * scale);
  o[2] = (bf16)(v.z * scale); o[3] = (bf16)(v.w * scale);
  *(bf16x4*)dst = o;
}

// ---------------------------------------------------------------------------
// Kernel 2: QKV projection with FUSED RoPE + V-transpose epilogue.
// Q -> Qh [bh][s][64] (linear), K -> Kh [bh][s][64] with the d-dimension
// PRE-SWIZZLED per row (element (s,d) stored at d ^ ((s&7)<<3)) so attn can
// stage K-tiles linearly via global_load_lds and read conflict-free with the
// inverse XOR. V -> Vt[bh][64][2048] with s-within-64 pre-swizzled by d.
// Both-sides swizzle pattern (m173).
// ---------------------------------------------------------------------------
__global__ __launch_bounds__(256) void gemm_qkv(
    const bf16* __restrict__ A, const bf16* __restrict__ B,
    bf16* __restrict__ Qh, bf16* __restrict__ Kh, bf16* __restrict__ Vt,
    int K) {
  __shared__ __align__(16) bf16 As[128 * 32];
  __shared__ __align__(16) bf16 Bs[128 * 32];
  const int tid = threadIdx.x;
  const int wave = tid >> 6, lane = tid & 63;
  const int bm = blockIdx.y * 128, bn = blockIdx.x * 128;
  const int wm = (wave >> 1) * 64, wn = (wave & 1) * 64;
  const int lrow = lane >> 2, lk = (lane & 3) * 8;
  const int fr = lane & 15, fk = (lane >> 4) * 8;

  f32x4 acc[4][4] = {};

  for (int kt = 0; kt < K; kt += 32) {
    __syncthreads();
#pragma unroll
    for (int c = 0; c < 2; ++c) {
      const int chunk = wave * 2 + c;
      const bf16* ga = A + (size_t)(bm + chunk * 16 + lrow) * K + kt + lk;
      async_load16(ga, (void*)(As + chunk * 512));
      const bf16* gb = B + (size_t)(bn + chunk * 16 + lrow) * K + kt + lk;
      async_load16(gb, (void*)(Bs + chunk * 512));
    }
    __syncthreads();

    bf16x8 af[4], bfr[4];
#pragma unroll
    for (int i = 0; i < 4; ++i)
      af[i] = *(const bf16x8*)&As[(wm + i * 16 + fr) * 32 + fk];
#pragma unroll
    for (int j = 0; j < 4; ++j)
      bfr[j] = *(const bf16x8*)&Bs[(wn + j * 16 + fr) * 32 + fk];
#pragma unroll
    for (int i = 0; i < 4; ++i)
#pragma unroll
      for (int j = 0; j < 4; ++j)
        acc[i][j] =
            __builtin_amdgcn_mfma_f32_16x16x32_bf16(af[i], bfr[j], acc[i][j], 0, 0, 0);
  }

  const int r0 = (lane >> 4) * 4, cc = lane & 15;
  const bool oddl = cc & 1;
#pragma unroll
  for (int i = 0; i < 4; ++i) {
    const int row0 = bm + wm + i * 16 + r0;
    const int b = row0 >> 11, s0 = row0 & 2047;
#pragma unroll
    for (int j = 0; j < 4; ++j) {
      const int col = bn + wn + j * 16 + cc;  // whole wave same region per j
      if (col < 2048) {
        // RoPE: pair partner is lane^1 (col 2k <-> 2k+1)
        const int hcol = col & 1023;
        const int h = hcol >> 6, d = hcol & 63;
        const int ip = d >> 1;
        const float freq = __expf((float)ip * -0.2878231366242557f);
        const bool isK = col >= 1024;
        bf16* dst = (isK ? Kh : Qh) + ((size_t)(b * 16 + h) * 2048) * 64;
#pragma unroll
        for (int r = 0; r < 4; ++r) {
          float own = acc[i][j][r];
          float oth = __shfl_xor(own, 1, 64);
          float sn, cs;
          __sincosf((float)(s0 + r) * freq, &sn, &cs);
          float res = oddl ? (oth * sn + own * cs) : (own * cs - oth * sn);
          // K: d-swizzle by row (bits 3..5 of d; rope pair bit0 unaffected)
          const int dd = isK ? (d ^ (((s0 + r) & 7) << 3)) : d;
          dst[(size_t)(s0 + r) * 64 + dd] = (bf16)res;
        }
      } else {
        const int v = col - 2048, h = v >> 6, d = v & 63;
        bf16x4 o;
#pragma unroll
        for (int r = 0; r < 4; ++r) o[r] = (bf16)acc[i][j][r];
        // pre-swizzled column (XOR touches bits 3..5 only; the 4-run at s0
        // stays contiguous since s0 is 4-aligned)
        const int s2 = (s0 & ~63) | ((s0 ^ ((d & 7) << 3)) & 63);
        *(bf16x4*)&Vt[(((size_t)b * 16 + h) * 64 + d) * 2048 + s2] = o;
      }
    }
  }
}

// ---------------------------------------------------------------------------
// Kernel 2b (out-proj): C(MxN) = A(MxK) @ B(NxK)^T, fp32 out.
// 128x128 tile (256 blocks = exact 1/CU).
// ---------------------------------------------------------------------------
template <typename OutT, int BM, int BN>
__global__ __launch_bounds__(256) void gemm_bt(
    const bf16* __restrict__ A, const bf16* __restrict__ B,
    OutT* __restrict__ C, int M, int N, int K) {
  constexpr int ACH = BM / 16, NCH = (BM + BN) / 16, PW = NCH / 4;
  constexpr int FM = BM / 32, FN = BN / 32;
  __shared__ __align__(16) bf16 As[BM * 32];
  __shared__ __align__(16) bf16 Bs[BN * 32];
  const int tid = threadIdx.x;
  const int wave = tid >> 6, lane = tid & 63;
  const int bm = blockIdx.y * BM, bn = blockIdx.x * BN;
  const int wm = (wave >> 1) * (BM / 2), wn = (wave & 1) * (BN / 2);
  const int lrow = lane >> 2, lk = (lane & 3) * 8;
  const int fr = lane & 15, fk = (lane >> 4) * 8;

  f32x4 acc[FM][FN] = {};

  for (int kt = 0; kt < K; kt += 32) {
    __syncthreads();
#pragma unroll
    for (int c = 0; c < PW; ++c) {
      const int chunk = wave * PW + c;
      if (chunk < ACH) {
        const bf16* ga = A + (size_t)(bm + chunk * 16 + lrow) * K + kt + lk;
        async_load16(ga, (void*)(As + chunk * 512));
      } else {
        const int bc = chunk - ACH;
        const bf16* gb = B + (size_t)(bn + bc * 16 + lrow) * K + kt + lk;
        async_load16(gb, (void*)(Bs + bc * 512));
      }
    }
    __syncthreads();

    bf16x8 af[FM], bfr[FN];
#pragma unroll
    for (int i = 0; i < FM; ++i)
      af[i] = *(const bf16x8*)&As[(wm + i * 16 + fr) * 32 + fk];
#pragma unroll
    for (int j = 0; j < FN; ++j)
      bfr[j] = *(const bf16x8*)&Bs[(wn + j * 16 + fr) * 32 + fk];
#pragma unroll
    for (int i = 0; i < FM; ++i)
#pragma unroll
      for (int j = 0; j < FN; ++j)
        acc[i][j] =
            __builtin_amdgcn_mfma_f32_16x16x32_bf16(af[i], bfr[j], acc[i][j], 0, 0, 0);
  }

  const int r0 = (lane >> 4) * 4, cc = lane & 15;
#pragma unroll
  for (int i = 0; i < FM; ++i)
#pragma unroll
    for (int j = 0; j < FN; ++j)
#pragma unroll
      for (int r = 0; r < 4; ++r)
        C[(size_t)(bm + wm + i * 16 + r0 + r) * N + (bn + wn + j * 16 + cc)] =
            (OutT)acc[i][j][r];
}

// ---------------------------------------------------------------------------
// Kernel 3: causal attention — ROUND 17: in-wave software pipeline.
// r16 post-mortem: 3 different data-movement structures all hit ~50us at
// MfmaUtil 19% -> bottleneck is the per-tile SERIAL chain
// (Kread -> QK -> exp(400cy VALU) -> Vread -> PV(600cy)) with ~1 resident
// block/CU (Occupancy 11.5%). Fixes:
//   * Pipeline across tiles: per iter do QK(i+1) then PV(i) (MFMA pipe
//     back-to-back), then exp(i+1) on the VALU pipe overlapping the MFMA
//     drain. Single P buffer (PV(i) reads p before exp(i+1) overwrites;
//     in-order WAR). Needs K(i+1) staged one tile ahead -> 3 LDS slots.
//   * Deterministic complementary pairing: block f and f+256 (same CU when
//     the 2-deep grid fills) get q-tiles j and 15-j -> every CU totals
//     exactly 34 tile-iters (LPT worst CU was ~48).
//   * s_setprio(1) around the merged MFMA burst (T5).
// Guards are wave-uniform (nw = 2j+(w>>1)+1 tiles for wave w); barriers
// unconditional and uniform.
// ---------------------------------------------------------------------------
__global__ __launch_bounds__(256, 2) void attn(const bf16* __restrict__ Qh,
                                               const bf16* __restrict__ Kh,
                                               const bf16* __restrict__ Vt,
                                               bf16* __restrict__ Oh) {
  __shared__ __align__(16) bf16 Ks[3][64 * 64];
  __shared__ __align__(16) bf16 Vs[3][64 * 64];
  const int f = blockIdx.x;
  int j, bh;
  if (f < 256) { bh = f >> 4;              j = 15 - (f & 15); }
  else         { bh = 16 + ((f - 256) >> 4); j = f & 15; }
  const int tid = threadIdx.x, w = tid >> 6, lane = tid & 63;
  const int nlo = lane & 15, g = lane >> 4;
  const int q0 = j * 128, qw0 = q0 + w * 32;  // this wave's 32 q-rows
  const bf16* __restrict__ Qp = Qh + (size_t)bh * 131072;
  const bf16* __restrict__ Kp = Kh + (size_t)bh * 131072;
  const bf16* __restrict__ Vp = Vt + (size_t)bh * 131072;
  const int n = 2 * (j + 1);            // k-tiles for this block
  const int nw = 2 * j + (w >> 1) + 1;  // k-tiles this wave computes

  // Q fragments (B-operand: n=q=nlo, k=d), linear Qh
  bf16x8 aq[2][2];
#pragma unroll
  for (int qb = 0; qb < 2; ++qb)
#pragma unroll
    for (int ks = 0; ks < 2; ++ks)
      aq[qb][ks] =
          *(const bf16x8*)&Qp[(size_t)(qw0 + qb * 16 + nlo) * 64 + ks * 32 + g * 8];

  f32x4 oacc[2][4] = {};  // [qb][d-block], O^T C-layout (m=d, n=q)
  float lsum[2] = {0.f, 0.f};
  const int sw = (nlo & 7) << 3;  // inverse XOR for swizzled LDS reads

  // Staging: wave w stages rows w*16..w*16+15 of each 64x64 tile.
  const int srow = w * 16 + (lane >> 3);
  const int soff = (lane & 7) * 8;

  auto stage = [&](int slot, int kbase) {
    async_load16(Kp + (size_t)(kbase + srow) * 64 + soff,
                 (void*)(Ks[slot] + w * 1024));
    async_load16(Kp + (size_t)(kbase + srow + 8) * 64 + soff,
                 (void*)(Ks[slot] + w * 1024 + 512));
    async_load16(Vp + (size_t)srow * 2048 + kbase + soff,
                 (void*)(Vs[slot] + w * 1024));
    async_load16(Vp + (size_t)(srow + 8) * 2048 + kbase + soff,
                 (void*)(Vs[slot] + w * 1024 + 512));
  };

  bf16x8 pk[4][2];
  auto rdK = [&](int slot) {
    const bf16* __restrict__ Kw = Ks[slot];
#pragma unroll
    for (int ni = 0; ni < 4; ++ni)
#pragma unroll
      for (int ks = 0; ks < 2; ++ks)
        pk[ni][ks] =
            *(const bf16x8*)&Kw[(ni * 16 + nlo) * 64 + ((ks * 32 + g * 8) ^ sw)];
  };

  bf16x4 av[4][4];
  auto rdV = [&](int slot) {
    const bf16* __restrict__ Vw = Vs[slot];
#pragma unroll
    for (int ni = 0; ni < 4; ++ni)
#pragma unroll
      for (int mi = 0; mi < 4; ++mi)
        av[ni][mi] =
            *(const bf16x4*)&Vw[(mi * 16 + nlo) * 64 + ((ni * 16 + g * 4) ^ sw)];
  };

  f32x4 st[2][4];
  auto qk = [&]() {
#pragma unroll
    for (int qb = 0; qb < 2; ++qb) {
#pragma unroll
      for (int ni = 0; ni < 4; ++ni) st[qb][ni] = f32x4{0.f, 0.f, 0.f, 0.f};
#pragma unroll
      for (int ks = 0; ks < 2; ++ks)
#pragma unroll
        for (int ni = 0; ni < 4; ++ni)
          st[qb][ni] = __builtin_amdgcn_mfma_f32_16x16x32_bf16(
              pk[ni][ks], aq[qb][ks], st[qb][ni], 0, 0, 0);
    }
  };

  bf16x4 p[2][4];
  auto expv = [&](int i) {
    const int kbase = i * 64;
    const bool dg = (i == nw - 1);  // diagonal tile (wave-uniform)
#pragma unroll
    for (int qb = 0; qb < 2; ++qb) {
      const int qg = qw0 + qb * 16 + nlo;
      if (!dg) {
#pragma unroll
        for (int ni = 0; ni < 4; ++ni)
#pragma unroll
          for (int r = 0; r < 4; ++r) {
            float e = __builtin_amdgcn_exp2f(st[qb][ni][r]);
            lsum[qb] += e;
            p[qb][ni][r] = (bf16)e;
          }
      } else {
#pragma unroll
        for (int ni = 0; ni < 4; ++ni) {
          const int kg0 = kbase + ni * 16 + g * 4;
#pragma unroll
          for (int r = 0; r < 4; ++r) {
            float e = __builtin_amdgcn_exp2f(st[qb][ni][r]);
            e = (kg0 + r <= qg) ? e : 0.0f;
            lsum[qb] += e;
            p[qb][ni][r] = (bf16)e;
          }
        }
      }
    }
  };

  auto pv = [&]() {
#pragma unroll
    for (int ni = 0; ni < 4; ++ni)
#pragma unroll
      for (int mi = 0; mi < 4; ++mi)
#pragma unroll
        for (int qb = 0; qb < 2; ++qb)
          oacc[qb][mi] = mfma16(av[ni][mi], p[qb][ni], oacc[qb][mi]);
  };

  // ---- prologue: stage tiles 0,1; compute P(0) ----
  stage(0, 0);
  stage(1, 64);
  __syncthreads();  // drains vmcnt -> slots 0,1 staged
  rdK(0);
  qk();
  expv(0);

  // ---- pipelined main loop: iter i does QK(i+1) + PV(i) ----
  for (int i = 0; i < n - 1; ++i) {
    const int i1 = i + 1;
    if (i + 2 < n) stage((i + 2) % 3, (i + 2) * 64);
    const bool doQK = (i1 < nw);  // wave-uniform
    if (doQK) rdK(i1 % 3);
    rdV(i % 3);  // i < nw for all loop iters (nw >= n-1)
    __builtin_amdgcn_s_setprio(1);
    if (doQK) qk();
    pv();  // PV(i)
    __builtin_amdgcn_s_setprio(0);
    if (doQK) expv(i1);
    __syncthreads();  // slot (i+2) staged; tile i's V free for reuse
  }

  // ---- epilogue: waves owning the last tile finish PV(n-1) ----
  if (nw == n) {
    rdV((n - 1) % 3);
    pv();
  }

  // finish l: reduce over the 4 g-groups (columns are per-nlo)
#pragma unroll
  for (int qb = 0; qb < 2; ++qb) {
    lsum[qb] += __shfl_xor(lsum[qb], 16, 64);
    lsum[qb] += __shfl_xor(lsum[qb], 32, 64);
  }

  // each wave writes its own rows; no combine needed
  const int bb = bh >> 4, hd = bh & 15;
#pragma unroll
  for (int qb = 0; qb < 2; ++qb) {
    const float inv = 1.0f / lsum[qb];
    const int q = qw0 + qb * 16 + nlo;
#pragma unroll
    for (int mi = 0; mi < 4; ++mi) {
      bf16x4 o;
#pragma unroll
      for (int r = 0; r < 4; ++r) o[r] = (bf16)(oacc[qb][mi][r] * inv);
      *(bf16x4*)&Oh[((size_t)bb * 2048 + q) * 1024 + hd * 64 + mi * 16 + g * 4] = o;
    }
  }
}

// ---------------------------------------------------------------------------
extern "C" void kernel_launch(void* const* d_in, const int* in_sizes, int n_in,
                              void* d_out, int out_size, void* d_ws, size_t ws_size,
                              hipStream_t stream) {
  (void)in_sizes; (void)n_in; (void)out_size; (void)ws_size;
  const float* x = (const float*)d_in[0];
  const float* Wq = (const float*)d_in[1];
  const float* Wk = (const float*)d_in[2];
  const float* Wv = (const float*)d_in[3];
  const float* Wo = (const float*)d_in[4];
  float* out = (float*)d_out;
  char* ws = (char*)d_ws;

  bf16* Xh   = (bf16*)(ws);                 // 4096x1024          8 MB
  bf16* Wqkv = (bf16*)(ws + 8388608);       // 3072x1024          6 MB
  bf16* Woh  = (bf16*)(ws + 14680064);      // 1024x1024          2 MB
  bf16* Qh   = (bf16*)(ws + 16777216);      // [32][2048][64]     8 MB
  bf16* Kh   = (bf16*)(ws + 25165824);      // [32][2048][64]     8 MB (d-swizzled)
  bf16* Vt   = (bf16*)(ws + 33554432);      // [32][64][2048]     8 MB (col-swizzled)
  bf16* Oh   = (bf16*)(ws + 41943040);      // 4096x1024          8 MB

  cast_all<<<8192, 256, 0, stream>>>(x, Wq, Wk, Wv, Wo, Xh, Wqkv, Woh);
  gemm_qkv<<<dim3(24, 32), 256, 0, stream>>>(Xh, Wqkv, Qh, Kh, Vt, 1024);
  attn<<<512, 256, 0, stream>>>(Qh, Kh, Vt, Oh);
  gemm_bt<float, 128, 128><<<dim3(8, 32), 256, 0, stream>>>(Oh, Woh, out, 4096, 1024, 1024);
}

// Round 4
// 178.143 us; speedup vs baseline: 1.0934x; 1.0663x over previous
//
#include <hip/hip_runtime.h>
#include <stdint.h>
#include <stddef.h>

typedef __bf16 bf16;
typedef __bf16 bf16x8 __attribute__((ext_vector_type(8)));
typedef __bf16 bf16x4 __attribute__((ext_vector_type(4)));
typedef short short4v __attribute__((ext_vector_type(4)));
typedef float f32x4 __attribute__((ext_vector_type(4)));

#define GAS __attribute__((address_space(1)))
#define LAS __attribute__((address_space(3)))

__device__ __forceinline__ void async_load16(const void* g, void* l) {
  __builtin_amdgcn_global_load_lds((const GAS void*)g, (LAS void*)l, 16, 0, 0);
}

// 16x16x16 bf16 MFMA. C-layout of a 16x16 MFMA == B-layout of this shape,
// so P^T feeds PV straight from registers. Host pass gets a stub.
__device__ __forceinline__ f32x4 mfma16(bf16x4 a, bf16x4 b, f32x4 c) {
#if defined(__HIP_DEVICE_COMPILE__)
#if __has_builtin(__builtin_amdgcn_mfma_f32_16x16x16bf16_1k)
  return __builtin_amdgcn_mfma_f32_16x16x16bf16_1k(
      __builtin_bit_cast(short4v, a), __builtin_bit_cast(short4v, b), c, 0, 0, 0);
#else
  f32x4 d;
  asm volatile("v_mfma_f32_16x16x16_bf16 %0, %1, %2, %3"
               : "=v"(d)
               : "v"(a), "v"(b), "v"(c));
  return d;
#endif
#else
  (void)a; (void)b;
  return c;
#endif
}

// ---------------------------------------------------------------------------
// Kernel 1: fp32 -> bf16 casts, x4 vectorized. Wq pre-scaled by 0.125*log2(e)
// so QK^T lands in the exp2 domain. Blocks >= 8192 build the RoPE cos/sin
// table rope[s][ip] (float2, 2048x32 = 512KB) so gemm_qkv's epilogue does
// table loads instead of 64 __sincosf per thread.
// ---------------------------------------------------------------------------
__global__ __launch_bounds__(256) void cast_all(
    const float* __restrict__ x, const float* __restrict__ Wq,
    const float* __restrict__ Wk, const float* __restrict__ Wv,
    const float* __restrict__ Wo, bf16* __restrict__ Xh,
    bf16* __restrict__ Wqkv, bf16* __restrict__ Woh,
    float2* __restrict__ rope) {
  if (blockIdx.x >= 8192) {
    // RoPE table: entry e -> s = e>>5, ip = e&31 (4 per thread, same s).
    const int e = ((blockIdx.x - 8192) * 256 + threadIdx.x) * 4;
    const int s = e >> 5, ip0 = e & 31;
#pragma unroll
    for (int r = 0; r < 4; ++r) {
      const float freq = __expf((float)(ip0 + r) * -0.2878231366242557f);
      float sn, cs;
      __sincosf((float)s * freq, &sn, &cs);
      rope[e + r] = make_float2(cs, sn);
    }
    return;
  }
  int idx = (blockIdx.x * 256 + threadIdx.x) * 4;
  const float* src;
  bf16* dst;
  float scale = 1.0f;
  if (idx < 4194304) {
    src = x + idx; dst = Xh + idx;
  } else if (idx < 7340032) {
    int j = idx - 4194304;
    if (j < 1048576) {
      src = Wq + j; scale = 0.18033688011112042f;
    } else {
      src = ((j < 2097152) ? Wk : Wv) + (j & 1048575);
    }
    dst = Wqkv + j;
  } else {
    int j = idx - 7340032;
    src = Wo + j; dst = Woh + j;
  }
  float4 v = *(const float4*)src;
  bf16x4 o;
  o[0] = (bf16)(v.x * scale); o[1] = (bf16)(v.y * scale);
  o[2] = (bf16)(v.z * scale); o[3] = (bf16)(v.w * scale);
  *(bf16x4*)dst = o;
}

// ---------------------------------------------------------------------------
// Kernel 2: QKV projection with FUSED RoPE + V-transpose epilogue.
// ROUND 18 rebuild of the main loop (r17 counters: 410 TF, MfmaUtil 16%,
// VALUBusy 34% from sincos epilogue, 3.1M LDS bank conflicts from 8-way
// row-stride-64B fragment reads):
//   * BK=64 (16 K-steps, half the barrier drains).
//   * LDS XOR-swizzle k ^= (row&7)*8, applied on the GLOBAL source address
//     at staging (LDS dest stays linear for global_load_lds; both-sides
//     pattern m173). Fragment reads become 2-way conflicts (free, m136).
//   * RoPE epilogue reads the precomputed cos/sin table (no transcendentals).
// Outputs unchanged: Q -> Qh [bh][s][64] linear; K -> Kh d-swizzled
// (d ^ ((s&7)<<3)); V -> Vt[bh][64][2048] s-swizzled by d.
// ---------------------------------------------------------------------------
__global__ __launch_bounds__(256, 3) void gemm_qkv(
    const bf16* __restrict__ A, const bf16* __restrict__ B,
    const float2* __restrict__ rope, bf16* __restrict__ Qh,
    bf16* __restrict__ Kh, bf16* __restrict__ Vt, int K) {
  __shared__ __align__(16) bf16 As[128 * 64];
  __shared__ __align__(16) bf16 Bs[128 * 64];
  const int tid = threadIdx.x;
  const int wave = tid >> 6, lane = tid & 63;
  const int bm = blockIdx.y * 128, bn = blockIdx.x * 128;
  const int wm = (wave >> 1) * 64, wn = (wave & 1) * 64;
  const int fr = lane & 15, g = lane >> 4;
  const int sw8 = (fr & 7) * 8;  // read-side swizzle

  // Staging geometry: instr s covers rows s*32 + (tid>>3); each thread 16B.
  // Global column pre-swizzled so LDS(row,k) = G(row, k ^ (row&7)*8).
  const int srow = tid >> 3;
  const int scol = 8 * ((tid & 7) ^ (srow & 7));
  // LDS dest: wave-uniform base (+ lane*16B implicit)
  const int ldst = wave * 512;  // elems within each 2048-elem instr stripe

  f32x4 acc[4][4] = {};

  for (int kt = 0; kt < K; kt += 64) {
    __syncthreads();
#pragma unroll
    for (int s = 0; s < 4; ++s) {
      const int row = s * 32 + srow;
      async_load16(A + (size_t)(bm + row) * K + kt + scol,
                   (void*)(As + s * 2048 + ldst));
      async_load16(B + (size_t)(bn + row) * K + kt + scol,
                   (void*)(Bs + s * 2048 + ldst));
    }
    __syncthreads();

#pragma unroll
    for (int ks = 0; ks < 2; ++ks) {
      bf16x8 af[4], bfr[4];
      const int kq = (ks * 32 + g * 8) ^ sw8;
#pragma unroll
      for (int i = 0; i < 4; ++i)
        af[i] = *(const bf16x8*)&As[(wm + i * 16 + fr) * 64 + kq];
#pragma unroll
      for (int j = 0; j < 4; ++j)
        bfr[j] = *(const bf16x8*)&Bs[(wn + j * 16 + fr) * 64 + kq];
#pragma unroll
      for (int i = 0; i < 4; ++i)
#pragma unroll
        for (int j = 0; j < 4; ++j)
          acc[i][j] = __builtin_amdgcn_mfma_f32_16x16x32_bf16(af[i], bfr[j],
                                                              acc[i][j], 0, 0, 0);
    }
  }

  const int r0 = (lane >> 4) * 4, cc = lane & 15;
  const bool oddl = cc & 1;
#pragma unroll
  for (int i = 0; i < 4; ++i) {
    const int row0 = bm + wm + i * 16 + r0;
    const int b = row0 >> 11, s0 = row0 & 2047;
#pragma unroll
    for (int j = 0; j < 4; ++j) {
      const int col = bn + wn + j * 16 + cc;  // whole wave same region per j
      if (col < 2048) {
        // RoPE: pair partner is lane^1 (col 2k <-> 2k+1)
        const int hcol = col & 1023;
        const int h = hcol >> 6, d = hcol & 63;
        const int ip = d >> 1;
        const bool isK = col >= 1024;
        bf16* dst = (isK ? Kh : Qh) + ((size_t)(b * 16 + h) * 2048) * 64;
#pragma unroll
        for (int r = 0; r < 4; ++r) {
          float own = acc[i][j][r];
          float oth = __shfl_xor(own, 1, 64);
          const float2 t = rope[((s0 + r) << 5) + ip];
          float res = oddl ? (oth * t.y + own * t.x) : (own * t.x - oth * t.y);
          // K: d-swizzle by row (bits 3..5 of d; rope pair bit0 unaffected)
          const int dd = isK ? (d ^ (((s0 + r) & 7) << 3)) : d;
          dst[(size_t)(s0 + r) * 64 + dd] = (bf16)res;
        }
      } else {
        const int v = col - 2048, h = v >> 6, d = v & 63;
        bf16x4 o;
#pragma unroll
        for (int r = 0; r < 4; ++r) o[r] = (bf16)acc[i][j][r];
        // pre-swizzled column (XOR touches bits 3..5 only; the 4-run at s0
        // stays contiguous since s0 is 4-aligned)
        const int s2 = (s0 & ~63) | ((s0 ^ ((d & 7) << 3)) & 63);
        *(bf16x4*)&Vt[(((size_t)b * 16 + h) * 64 + d) * 2048 + s2] = o;
      }
    }
  }
}

// ---------------------------------------------------------------------------
// Kernel 2b (out-proj): C(MxN) = A(MxK) @ B(NxK)^T, fp32 out.
// 128x128 tile (256 blocks = exact 1/CU).
// ---------------------------------------------------------------------------
template <typename OutT, int BM, int BN>
__global__ __launch_bounds__(256) void gemm_bt(
    const bf16* __restrict__ A, const bf16* __restrict__ B,
    OutT* __restrict__ C, int M, int N, int K) {
  constexpr int ACH = BM / 16, NCH = (BM + BN) / 16, PW = NCH / 4;
  constexpr int FM = BM / 32, FN = BN / 32;
  __shared__ __align__(16) bf16 As[BM * 32];
  __shared__ __align__(16) bf16 Bs[BN * 32];
  const int tid = threadIdx.x;
  const int wave = tid >> 6, lane = tid & 63;
  const int bm = blockIdx.y * BM, bn = blockIdx.x * BN;
  const int wm = (wave >> 1) * (BM / 2), wn = (wave & 1) * (BN / 2);
  const int lrow = lane >> 2, lk = (lane & 3) * 8;
  const int fr = lane & 15, fk = (lane >> 4) * 8;

  f32x4 acc[FM][FN] = {};

  for (int kt = 0; kt < K; kt += 32) {
    __syncthreads();
#pragma unroll
    for (int c = 0; c < PW; ++c) {
      const int chunk = wave * PW + c;
      if (chunk < ACH) {
        const bf16* ga = A + (size_t)(bm + chunk * 16 + lrow) * K + kt + lk;
        async_load16(ga, (void*)(As + chunk * 512));
      } else {
        const int bc = chunk - ACH;
        const bf16* gb = B + (size_t)(bn + bc * 16 + lrow) * K + kt + lk;
        async_load16(gb, (void*)(Bs + bc * 512));
      }
    }
    __syncthreads();

    bf16x8 af[FM], bfr[FN];
#pragma unroll
    for (int i = 0; i < FM; ++i)
      af[i] = *(const bf16x8*)&As[(wm + i * 16 + fr) * 32 + fk];
#pragma unroll
    for (int j = 0; j < FN; ++j)
      bfr[j] = *(const bf16x8*)&Bs[(wn + j * 16 + fr) * 32 + fk];
#pragma unroll
    for (int i = 0; i < FM; ++i)
#pragma unroll
      for (int j = 0; j < FN; ++j)
        acc[i][j] =
            __builtin_amdgcn_mfma_f32_16x16x32_bf16(af[i], bfr[j], acc[i][j], 0, 0, 0);
  }

  const int r0 = (lane >> 4) * 4, cc = lane & 15;
#pragma unroll
  for (int i = 0; i < FM; ++i)
#pragma unroll
    for (int j = 0; j < FN; ++j)
#pragma unroll
      for (int r = 0; r < 4; ++r)
        C[(size_t)(bm + wm + i * 16 + r0 + r) * N + (bn + wn + j * 16 + cc)] =
            (OutT)acc[i][j][r];
}

// ---------------------------------------------------------------------------
// Kernel 3: causal attention — round-17 in-wave software pipeline (UNCHANGED;
// it dropped out of rocprof top-5, i.e. every dispatch < 62.5us).
// Per iter: QK(i+1) MFMA + PV(i) MFMA back-to-back, exp(i+1) on VALU
// overlapping the MFMA drain; 3 LDS slots; complementary block pairing;
// setprio around the MFMA burst.
// ---------------------------------------------------------------------------
__global__ __launch_bounds__(256, 2) void attn(const bf16* __restrict__ Qh,
                                               const bf16* __restrict__ Kh,
                                               const bf16* __restrict__ Vt,
                                               bf16* __restrict__ Oh) {
  __shared__ __align__(16) bf16 Ks[3][64 * 64];
  __shared__ __align__(16) bf16 Vs[3][64 * 64];
  const int f = blockIdx.x;
  int j, bh;
  if (f < 256) { bh = f >> 4;              j = 15 - (f & 15); }
  else         { bh = 16 + ((f - 256) >> 4); j = f & 15; }
  const int tid = threadIdx.x, w = tid >> 6, lane = tid & 63;
  const int nlo = lane & 15, g = lane >> 4;
  const int q0 = j * 128, qw0 = q0 + w * 32;  // this wave's 32 q-rows
  const bf16* __restrict__ Qp = Qh + (size_t)bh * 131072;
  const bf16* __restrict__ Kp = Kh + (size_t)bh * 131072;
  const bf16* __restrict__ Vp = Vt + (size_t)bh * 131072;
  const int n = 2 * (j + 1);            // k-tiles for this block
  const int nw = 2 * j + (w >> 1) + 1;  // k-tiles this wave computes

  // Q fragments (B-operand: n=q=nlo, k=d), linear Qh
  bf16x8 aq[2][2];
#pragma unroll
  for (int qb = 0; qb < 2; ++qb)
#pragma unroll
    for (int ks = 0; ks < 2; ++ks)
      aq[qb][ks] =
          *(const bf16x8*)&Qp[(size_t)(qw0 + qb * 16 + nlo) * 64 + ks * 32 + g * 8];

  f32x4 oacc[2][4] = {};  // [qb][d-block], O^T C-layout (m=d, n=q)
  float lsum[2] = {0.f, 0.f};
  const int sw = (nlo & 7) << 3;  // inverse XOR for swizzled LDS reads

  // Staging: wave w stages rows w*16..w*16+15 of each 64x64 tile.
  const int srow = w * 16 + (lane >> 3);
  const int soff = (lane & 7) * 8;

  auto stage = [&](int slot, int kbase) {
    async_load16(Kp + (size_t)(kbase + srow) * 64 + soff,
                 (void*)(Ks[slot] + w * 1024));
    async_load16(Kp + (size_t)(kbase + srow + 8) * 64 + soff,
                 (void*)(Ks[slot] + w * 1024 + 512));
    async_load16(Vp + (size_t)srow * 2048 + kbase + soff,
                 (void*)(Vs[slot] + w * 1024));
    async_load16(Vp + (size_t)(srow + 8) * 2048 + kbase + soff,
                 (void*)(Vs[slot] + w * 1024 + 512));
  };

  bf16x8 pk[4][2];
  auto rdK = [&](int slot) {
    const bf16* __restrict__ Kw = Ks[slot];
#pragma unroll
    for (int ni = 0; ni < 4; ++ni)
#pragma unroll
      for (int ks = 0; ks < 2; ++ks)
        pk[ni][ks] =
            *(const bf16x8*)&Kw[(ni * 16 + nlo) * 64 + ((ks * 32 + g * 8) ^ sw)];
  };

  bf16x4 av[4][4];
  auto rdV = [&](int slot) {
    const bf16* __restrict__ Vw = Vs[slot];
#pragma unroll
    for (int ni = 0; ni < 4; ++ni)
#pragma unroll
      for (int mi = 0; mi < 4; ++mi)
        av[ni][mi] =
            *(const bf16x4*)&Vw[(mi * 16 + nlo) * 64 + ((ni * 16 + g * 4) ^ sw)];
  };

  f32x4 st[2][4];
  auto qk = [&]() {
#pragma unroll
    for (int qb = 0; qb < 2; ++qb) {
#pragma unroll
      for (int ni = 0; ni < 4; ++ni) st[qb][ni] = f32x4{0.f, 0.f, 0.f, 0.f};
#pragma unroll
      for (int ks = 0; ks < 2; ++ks)
#pragma unroll
        for (int ni = 0; ni < 4; ++ni)
          st[qb][ni] = __builtin_amdgcn_mfma_f32_16x16x32_bf16(
              pk[ni][ks], aq[qb][ks], st[qb][ni], 0, 0, 0);
    }
  };

  bf16x4 p[2][4];
  auto expv = [&](int i) {
    const int kbase = i * 64;
    const bool dg = (i == nw - 1);  // diagonal tile (wave-uniform)
#pragma unroll
    for (int qb = 0; qb < 2; ++qb) {
      const int qg = qw0 + qb * 16 + nlo;
      if (!dg) {
#pragma unroll
        for (int ni = 0; ni < 4; ++ni)
#pragma unroll
          for (int r = 0; r < 4; ++r) {
            float e = __builtin_amdgcn_exp2f(st[qb][ni][r]);
            lsum[qb] += e;
            p[qb][ni][r] = (bf16)e;
          }
      } else {
#pragma unroll
        for (int ni = 0; ni < 4; ++ni) {
          const int kg0 = kbase + ni * 16 + g * 4;
#pragma unroll
          for (int r = 0; r < 4; ++r) {
            float e = __builtin_amdgcn_exp2f(st[qb][ni][r]);
            e = (kg0 + r <= qg) ? e : 0.0f;
            lsum[qb] += e;
            p[qb][ni][r] = (bf16)e;
          }
        }
      }
    }
  };

  auto pv = [&]() {
#pragma unroll
    for (int ni = 0; ni < 4; ++ni)
#pragma unroll
      for (int mi = 0; mi < 4; ++mi)
#pragma unroll
        for (int qb = 0; qb < 2; ++qb)
          oacc[qb][mi] = mfma16(av[ni][mi], p[qb][ni], oacc[qb][mi]);
  };

  // ---- prologue: stage tiles 0,1; compute P(0) ----
  stage(0, 0);
  stage(1, 64);
  __syncthreads();  // drains vmcnt -> slots 0,1 staged
  rdK(0);
  qk();
  expv(0);

  // ---- pipelined main loop: iter i does QK(i+1) + PV(i) ----
  for (int i = 0; i < n - 1; ++i) {
    const int i1 = i + 1;
    if (i + 2 < n) stage((i + 2) % 3, (i + 2) * 64);
    const bool doQK = (i1 < nw);  // wave-uniform
    if (doQK) rdK(i1 % 3);
    rdV(i % 3);  // i < nw for all loop iters (nw >= n-1)
    __builtin_amdgcn_s_setprio(1);
    if (doQK) qk();
    pv();  // PV(i)
    __builtin_amdgcn_s_setprio(0);
    if (doQK) expv(i1);
    __syncthreads();  // slot (i+2) staged; tile i's V free for reuse
  }

  // ---- epilogue: waves owning the last tile finish PV(n-1) ----
  if (nw == n) {
    rdV((n - 1) % 3);
    pv();
  }

  // finish l: reduce over the 4 g-groups (columns are per-nlo)
#pragma unroll
  for (int qb = 0; qb < 2; ++qb) {
    lsum[qb] += __shfl_xor(lsum[qb], 16, 64);
    lsum[qb] += __shfl_xor(lsum[qb], 32, 64);
  }

  // each wave writes its own rows; no combine needed
  const int bb = bh >> 4, hd = bh & 15;
#pragma unroll
  for (int qb = 0; qb < 2; ++qb) {
    const float inv = 1.0f / lsum[qb];
    const int q = qw0 + qb * 16 + nlo;
#pragma unroll
    for (int mi = 0; mi < 4; ++mi) {
      bf16x4 o;
#pragma unroll
      for (int r = 0; r < 4; ++r) o[r] = (bf16)(oacc[qb][mi][r] * inv);
      *(bf16x4*)&Oh[((size_t)bb * 2048 + q) * 1024 + hd * 64 + mi * 16 + g * 4] = o;
    }
  }
}

// ---------------------------------------------------------------------------
extern "C" void kernel_launch(void* const* d_in, const int* in_sizes, int n_in,
                              void* d_out, int out_size, void* d_ws, size_t ws_size,
                              hipStream_t stream) {
  (void)in_sizes; (void)n_in; (void)out_size; (void)ws_size;
  const float* x = (const float*)d_in[0];
  const float* Wq = (const float*)d_in[1];
  const float* Wk = (const float*)d_in[2];
  const float* Wv = (const float*)d_in[3];
  const float* Wo = (const float*)d_in[4];
  float* out = (float*)d_out;
  char* ws = (char*)d_ws;

  bf16* Xh    = (bf16*)(ws);                 // 4096x1024          8 MB
  bf16* Wqkv  = (bf16*)(ws + 8388608);       // 3072x1024          6 MB
  bf16* Woh   = (bf16*)(ws + 14680064);      // 1024x1024          2 MB
  bf16* Qh    = (bf16*)(ws + 16777216);      // [32][2048][64]     8 MB
  bf16* Kh    = (bf16*)(ws + 25165824);      // [32][2048][64]     8 MB (d-swizzled)
  bf16* Vt    = (bf16*)(ws + 33554432);      // [32][64][2048]     8 MB (col-swizzled)
  bf16* Oh    = (bf16*)(ws + 41943040);      // 4096x1024          8 MB
  float2* rope = (float2*)(ws + 50331648);   // [2048][32] cos/sin 512 KB

  cast_all<<<8256, 256, 0, stream>>>(x, Wq, Wk, Wv, Wo, Xh, Wqkv, Woh, rope);
  gemm_qkv<<<dim3(24, 32), 256, 0, stream>>>(Xh, Wqkv, rope, Qh, Kh, Vt, 1024);
  attn<<<512, 256, 0, stream>>>(Qh, Kh, Vt, Oh);
  gemm_bt<float, 128, 128><<<dim3(8, 32), 256, 0, stream>>>(Oh, Woh, out, 4096, 1024, 1024);
}